// Round 5
// baseline (267.994 us; speedup 1.0000x reference)
//
#include <hip/hip_runtime.h>

#pragma clang fp contract(off)

typedef __attribute__((ext_vector_type(8))) short short8;
typedef __attribute__((ext_vector_type(4))) float f32x4;

#define MARGIN 0.02f

static __device__ __forceinline__ unsigned short f2b(float f) {
    union { float f; unsigned u; } x; x.f = f;
    unsigned u = x.u;
    return (unsigned short)((u + 0x7FFFu + ((u >> 16) & 1u)) >> 16);
}
static __device__ __forceinline__ float b2f(unsigned short u) {
    union { float f; unsigned u32; } x;
    x.u32 = ((unsigned)u) << 16;
    return x.f;
}

// Bit-exact emulation of np's distance for one (row, k):
// dot = BLAS sgemm: single accumulator, ascending k, FMA.
// d = (znorm - 2*dot) + enorm, each op single-rounded fp32.
static __device__ __forceinline__ float np_dist(
    const float* __restrict__ z, const float* __restrict__ E,
    float zn, float en, int row, int k) {
    const float* zr = z + row * 64;
    float c = 0.f;
    #pragma unroll
    for (int i = 0; i < 64; ++i) c = fmaf(zr[i], E[i * 1024 + k], c);
    float t = zn - 2.f * c;
    return t + en;
}

// ---------------------------------------------------------------------------
// Kernel 1: prep. ws: loss @ +0 (zeroed), enorm[1024] fp32 @ +128.
// enorm = np.sum(E*E, axis=0): outer-axis reduce -> sequential ascending d.
// (fmaf == mul+add here: bf16-valued operands, products exact.)
// ---------------------------------------------------------------------------
__global__ __launch_bounds__(256) void vq_prep(
    const float* __restrict__ E, float* __restrict__ ws_loss,
    float* __restrict__ enorm) {
    int c = blockIdx.x * 256 + threadIdx.x;  // 0..1023
    float s2 = 0.f;
    #pragma unroll
    for (int d = 0; d < 64; ++d) {
        float v = E[d * 1024 + c];
        s2 = fmaf(v, v, s2);
    }
    enorm[c] = s2;
    if (c == 0) *ws_loss = 0.f;
}

// ---------------------------------------------------------------------------
// Kernel 2: MFMA screening (top-2 per lane-slot) + bit-exact np re-evaluation
// of all candidates within MARGIN + gather + loss.
// Block = 256 (4 waves), 128 z-rows/block, grid = 1024.
// ---------------------------------------------------------------------------
__global__ __launch_bounds__(256) void vq_main(
    const float* __restrict__ z, const float* __restrict__ E,
    const float* __restrict__ enorm, float* __restrict__ ws_loss,
    float* __restrict__ out) {
    __shared__ unsigned short sB[256 * 64];  // 32 KB bf16 B-tile (swizzled)
    __shared__ float sEn[1024];              // np-exact codebook norms
    __shared__ float sZn[128];               // np-exact |z|^2 per row
    __shared__ int sIdx[128];
    __shared__ float sRed[4];

    const int tid = threadIdx.x;
    const int w = tid >> 6;
    const int l = tid & 63;
    const int quad = l >> 4;
    const int m = l & 15;
    const int b = blockIdx.x;

    ((float4*)sEn)[tid] = ((const float4*)enorm)[tid];

    // znorm: bit-exact numpy pairwise sum of z*z over 64 contiguous floats.
    // SIMD path, SSE baseline (4 lanes), 4 vector accumulators, SSE3-hadd
    // horizontal: S[u] = ((t[u]+t[16+u])+t[32+u])+t[48+u], u in [0,16);
    // R[l] = (S[l]+S[4+l]) + (S[8+l]+S[12+l]); zn = (R0+R1)+(R2+R3).
    if (tid < 128) {
        const float* zr = z + (b * 128 + tid) * 64;
        float S[16];
        #pragma unroll
        for (int u = 0; u < 16; ++u) { float v = zr[u]; S[u] = v * v; }
        #pragma unroll
        for (int t = 1; t < 4; ++t)
            #pragma unroll
            for (int u = 0; u < 16; ++u) {
                float v = zr[16 * t + u];
                float sq = v * v;          // exact (bf16-valued)
                S[u] = S[u] + sq;
            }
        float R0 = (S[0] + S[4]) + (S[8] + S[12]);
        float R1 = (S[1] + S[5]) + (S[9] + S[13]);
        float R2 = (S[2] + S[6]) + (S[10] + S[14]);
        float R3 = (S[3] + S[7]) + (S[11] + S[15]);
        sZn[tid] = (R0 + R1) + (R2 + R3);
    }

    // A fragments: fp32 -> bf16 (exact for bf16-valued inputs)
    short8 a[2][2];
    #pragma unroll
    for (int rt = 0; rt < 2; ++rt) {
        const int row = b * 128 + w * 32 + rt * 16 + m;
        #pragma unroll
        for (int s = 0; s < 2; ++s) {
            const float* zp = z + row * 64 + s * 32 + quad * 8;
            union { float4 v; float f[4]; } u0, u1;
            u0.v = *(const float4*)zp;
            u1.v = *(const float4*)(zp + 4);
            short8 av;
            #pragma unroll
            for (int j = 0; j < 4; ++j) av[j] = (short)f2b(u0.f[j]);
            #pragma unroll
            for (int j = 0; j < 4; ++j) av[4 + j] = (short)f2b(u1.f[j]);
            a[rt][s] = av;
        }
    }

    // screening: track top-2 (v, c) per slot, v = enorm - 2*dot
    float v1[2][4], v2[2][4];
    int k1[2][4], k2[2][4];
    #pragma unroll
    for (int rt = 0; rt < 2; ++rt)
        #pragma unroll
        for (int r = 0; r < 4; ++r) {
            v1[rt][r] = 3.4e38f; v2[rt][r] = 3.4e38f;
            k1[rt][r] = 0; k2[rt][r] = 0;
        }

    for (int st = 0; st < 4; ++st) {
        // stage 256 cols x 64 dims of E as bf16, XOR-swizzled 16B k-groups
        #pragma unroll
        for (int i = 0; i < 8; ++i) {
            const int u = tid + i * 256;
            const int d0 = (u & 31) * 2;
            const int cg = u >> 5;
            const float* e0 = E + d0 * 1024 + st * 256 + cg * 4;
            union { float4 v; float f[4]; } va, vb;
            va.v = *(const float4*)e0;
            vb.v = *(const float4*)(e0 + 1024);
            #pragma unroll
            for (int j = 0; j < 4; ++j) {
                const int col = cg * 4 + j;
                const unsigned lo = f2b(va.f[j]);
                const unsigned hi = f2b(vb.f[j]);
                const int gi = col * 8 + ((d0 >> 3) ^ (col & 7));
                *(unsigned*)&sB[gi * 8 + (d0 & 7)] = lo | (hi << 16);
            }
        }
        __syncthreads();

        #pragma unroll
        for (int ct = 0; ct < 16; ++ct) {
            const int c = st * 16 + ct;
            const int colb = (ct * 16 + m) * 8;
            short8 b0 = *(const short8*)&sB[(colb + (quad ^ (m & 7))) * 8];
            short8 b1 = *(const short8*)&sB[(colb + ((4 + quad) ^ (m & 7))) * 8];
            f32x4 acc0 = {0.f, 0.f, 0.f, 0.f};
            f32x4 acc1 = {0.f, 0.f, 0.f, 0.f};
            acc0 = __builtin_amdgcn_mfma_f32_16x16x32_bf16(a[0][0], b0, acc0, 0, 0, 0);
            acc0 = __builtin_amdgcn_mfma_f32_16x16x32_bf16(a[0][1], b1, acc0, 0, 0, 0);
            acc1 = __builtin_amdgcn_mfma_f32_16x16x32_bf16(a[1][0], b0, acc1, 0, 0, 0);
            acc1 = __builtin_amdgcn_mfma_f32_16x16x32_bf16(a[1][1], b1, acc1, 0, 0, 0);
            const float en = sEn[c * 16 + m];
            #pragma unroll
            for (int r = 0; r < 4; ++r) {
                float v0 = fmaf(-2.f, acc0[r], en);
                bool p1 = v0 < v1[0][r];
                bool p2 = v0 < v2[0][r];
                v2[0][r] = p1 ? v1[0][r] : (p2 ? v0 : v2[0][r]);
                k2[0][r] = p1 ? k1[0][r] : (p2 ? c : k2[0][r]);
                v1[0][r] = p1 ? v0 : v1[0][r];
                k1[0][r] = p1 ? c : k1[0][r];
                float w1 = fmaf(-2.f, acc1[r], en);
                bool q1 = w1 < v1[1][r];
                bool q2 = w1 < v2[1][r];
                v2[1][r] = q1 ? v1[1][r] : (q2 ? w1 : v2[1][r]);
                k2[1][r] = q1 ? k1[1][r] : (q2 ? c : k2[1][r]);
                v1[1][r] = q1 ? w1 : v1[1][r];
                k1[1][r] = q1 ? c : k1[1][r];
            }
        }
        __syncthreads();
    }

    // exact re-evaluation of candidates; lexicographic (d, k) argmin per row
    float la = 0.f;
    #pragma unroll
    for (int rt = 0; rt < 2; ++rt) {
        #pragma unroll
        for (int r = 0; r < 4; ++r) {
            float vb = v1[rt][r];
            #pragma unroll
            for (int mask = 1; mask <= 8; mask <<= 1)
                vb = fminf(vb, __shfl_xor(vb, mask));
            const int rowl = w * 32 + rt * 16 + quad * 4 + r;
            const int row = b * 128 + rowl;
            const float zn = sZn[rowl];
            float d = 3.4e38f;
            int kk = 0x7fffffff;
            if (v1[rt][r] <= vb + MARGIN) {
                kk = k1[rt][r] * 16 + m;
                d = np_dist(z, E, zn, sEn[kk], row, kk);
            }
            if (v2[rt][r] <= vb + MARGIN) {
                int kc = k2[rt][r] * 16 + m;
                float dd = np_dist(z, E, zn, sEn[kc], row, kc);
                if (dd < d || (dd == d && kc < kk)) { d = dd; kk = kc; }
            }
            #pragma unroll
            for (int mask = 1; mask <= 8; mask <<= 1) {
                float d2 = __shfl_xor(d, mask);
                int c2 = __shfl_xor(kk, mask);
                bool take = (d2 < d) || (d2 == d && c2 < kk);
                d = take ? d2 : d;
                kk = take ? c2 : kk;
            }
            if (m == 0) {
                sIdx[rowl] = kk;
                la += d;
            }
        }
    }
    __syncthreads();

    // gather: 2 lanes/row, 32 dims each, fp32 from E (L2-hot)
    {
        const int row_local = w * 32 + (l >> 1);
        const int half = l & 1;
        const int idx = sIdx[row_local];
        union { float s[32]; float4 f[8]; } tmp;
        #pragma unroll
        for (int dd = 0; dd < 32; ++dd) tmp.s[dd] = E[(half * 32 + dd) * 1024 + idx];
        float4* dst = (float4*)(out + (b * 128 + row_local) * 64 + half * 32);
        #pragma unroll
        for (int q4 = 0; q4 < 8; ++q4) dst[q4] = tmp.f[q4];
    }

    #pragma unroll
    for (int mask = 32; mask >= 1; mask >>= 1) la += __shfl_xor(la, mask);
    if (l == 0) sRed[w] = la;
    __syncthreads();
    if (tid == 0) atomicAdd(ws_loss, sRed[0] + sRed[1] + sRed[2] + sRed[3]);
}

// ---------------------------------------------------------------------------
// Kernel 3: loss scalar (fp32) at out[8388608]
// ---------------------------------------------------------------------------
__global__ void vq_final(const float* __restrict__ ws_loss,
                         float* __restrict__ out) {
    out[8388608] = (*ws_loss) * (1.25f / 8388608.f);
}

extern "C" void kernel_launch(void* const* d_in, const int* in_sizes, int n_in,
                              void* d_out, int out_size, void* d_ws, size_t ws_size,
                              hipStream_t stream) {
    const float* z = (const float*)d_in[0];  // fp32 [131072,64] (bf16-valued)
    const float* E = (const float*)d_in[1];  // fp32 [64,1024]   (bf16-valued)
    float* out = (float*)d_out;              // fp32 [8388609]

    char* ws = (char*)d_ws;
    float* loss = (float*)ws;           // 4 B
    float* enorm = (float*)(ws + 128);  // 4 KB

    vq_prep<<<4, 256, 0, stream>>>(E, loss, enorm);
    vq_main<<<1024, 256, 0, stream>>>(z, E, enorm, loss, out);
    vq_final<<<1, 1, 0, stream>>>(loss, out);
}

// Round 7
// 176.241 us; speedup vs baseline: 1.5206x; 1.5206x over previous
//
#include <hip/hip_runtime.h>

#pragma clang fp contract(off)

typedef __attribute__((ext_vector_type(8))) short short8;
typedef __attribute__((ext_vector_type(4))) float f32x4;

#define MARGIN 0.02f

static __device__ __forceinline__ unsigned short f2b(float f) {
    union { float f; unsigned u; } x; x.f = f;
    unsigned u = x.u;
    return (unsigned short)((u + 0x7FFFu + ((u >> 16) & 1u)) >> 16);
}

// Bit-exact np distance: dot = single-accumulator ascending-k FMA chain
// (BLAS sgemm micro-kernel order) on FULL-PRECISION fp32 z from global;
// d = (zn - 2*dot) + en, each op single-rounded fp32.
// ES = element stride of the codebook column (1 for Et, 1024 for E).
template <int ES>
static __device__ __forceinline__ float np_dist(
    const float* __restrict__ zr, const float* __restrict__ ecol,
    float zn, float en) {
    float c = 0.f;
    #pragma unroll
    for (int i = 0; i < 64; ++i) c = fmaf(zr[i], ecol[i * ES], c);
    float t = zn - 2.f * c;
    return t + en;
}

// ---------------------------------------------------------------------------
// Kernel 0 (optional): transpose E -> Et[k*64+d] in ws (fp32, 256 KB).
// ---------------------------------------------------------------------------
__global__ __launch_bounds__(256) void vq_prep_t(
    const float* __restrict__ E, float* __restrict__ Et) {
    int t = blockIdx.x * 256 + threadIdx.x;  // 0..65535
    int k = t >> 6, d = t & 63;
    Et[t] = E[d * 1024 + k];
}

// ---------------------------------------------------------------------------
// Kernel 1: enorm[k] = sequential ascending-d sum of E[d][k]^2 (np axis-0
// reduce order); zero the loss accumulator. ES: 1 reading Et, 1024 reading E.
// ---------------------------------------------------------------------------
template <int ES>
__global__ __launch_bounds__(256) void vq_prep(
    const float* __restrict__ src, float* __restrict__ ws_loss,
    float* __restrict__ enorm) {
    int c = blockIdx.x * 256 + threadIdx.x;  // 0..1023
    const float* col = src + (ES == 1 ? c * 64 : c);
    float s2 = 0.f;
    #pragma unroll
    for (int d = 0; d < 64; ++d) {
        float v = col[d * ES];
        s2 = fmaf(v, v, s2);
    }
    enorm[c] = s2;
    if (c == 0) *ws_loss = 0.f;
}

// ---------------------------------------------------------------------------
// Kernel 2: MFMA screening (top-2 per lane-slot, margin 0.02 proven r5) +
// bit-exact re-eval (fp32 z from global, codebook col from Et) + gather +
// loss. Block = 256 (4 waves), 128 rows, grid = 1024. LDS ~21.5 KB.
// ---------------------------------------------------------------------------
template <bool USE_ET>
__global__ __launch_bounds__(256) void vq_main(
    const float* __restrict__ z, const float* __restrict__ E,
    const float* __restrict__ Et, const float* __restrict__ enorm,
    float* __restrict__ ws_loss, float* __restrict__ out) {
    __shared__ unsigned short sB[128 * 64];  // 16 KB swizzled bf16 B-tile
    __shared__ float sEn[1024];
    __shared__ float sZn[128];
    __shared__ int sIdx[128];
    __shared__ float sRed[4];

    const int tid = threadIdx.x;
    const int w = tid >> 6;
    const int l = tid & 63;
    const int quad = l >> 4;
    const int m = l & 15;
    const int b = blockIdx.x;

    ((float4*)sEn)[tid] = ((const float4*)enorm)[tid];

    // znorm: bit-exact numpy pairwise sum (SSE path, 4 accumulators, hadd).
    if (tid < 128) {
        const float* zr = z + (b * 128 + tid) * 64;
        float S[16];
        #pragma unroll
        for (int u = 0; u < 16; ++u) { float v = zr[u]; S[u] = v * v; }
        #pragma unroll
        for (int t = 1; t < 4; ++t)
            #pragma unroll
            for (int u = 0; u < 16; ++u) {
                float v = zr[16 * t + u];
                float sq = v * v;
                S[u] = S[u] + sq;
            }
        float R0 = (S[0] + S[4]) + (S[8] + S[12]);
        float R1 = (S[1] + S[5]) + (S[9] + S[13]);
        float R2 = (S[2] + S[6]) + (S[10] + S[14]);
        float R3 = (S[3] + S[7]) + (S[11] + S[15]);
        sZn[tid] = (R0 + R1) + (R2 + R3);
    }

    // A fragments (fp32 -> bf16 RNE for the screening MFMA)
    short8 a[2][2];
    #pragma unroll
    for (int rt = 0; rt < 2; ++rt) {
        const int rowl = w * 32 + rt * 16 + m;
        #pragma unroll
        for (int s = 0; s < 2; ++s) {
            const float* zp = z + (b * 128 + rowl) * 64 + s * 32 + quad * 8;
            union { float4 v; float f[4]; } u0, u1;
            u0.v = *(const float4*)zp;
            u1.v = *(const float4*)(zp + 4);
            short8 av;
            #pragma unroll
            for (int j = 0; j < 4; ++j) av[j] = (short)f2b(u0.f[j]);
            #pragma unroll
            for (int j = 0; j < 4; ++j) av[4 + j] = (short)f2b(u1.f[j]);
            a[rt][s] = av;
        }
    }

    // screening: top-2 (v, c) per slot, v = enorm - 2*dot
    float v1[2][4], v2[2][4];
    int k1[2][4], k2[2][4];
    #pragma unroll
    for (int rt = 0; rt < 2; ++rt)
        #pragma unroll
        for (int r = 0; r < 4; ++r) {
            v1[rt][r] = 3.4e38f; v2[rt][r] = 3.4e38f;
            k1[rt][r] = 0; k2[rt][r] = 0;
        }

    for (int st = 0; st < 8; ++st) {
        // stage 128 cols x 64 dims of E as bf16, XOR-swizzled 16B k-groups
        #pragma unroll
        for (int i = 0; i < 4; ++i) {
            const int u = tid + i * 256;       // 0..1023
            const int d0 = (u & 31) * 2;
            const int cg = u >> 5;             // 0..31 (4 cols each)
            const float* e0 = E + d0 * 1024 + st * 128 + cg * 4;
            union { float4 v; float f[4]; } va, vb;
            va.v = *(const float4*)e0;
            vb.v = *(const float4*)(e0 + 1024);
            #pragma unroll
            for (int j = 0; j < 4; ++j) {
                const int col = cg * 4 + j;    // local col 0..127
                const unsigned lo = f2b(va.f[j]);
                const unsigned hi = f2b(vb.f[j]);
                const int gi = col * 8 + ((d0 >> 3) ^ (col & 7));
                *(unsigned*)&sB[gi * 8 + (d0 & 7)] = lo | (hi << 16);
            }
        }
        __syncthreads();

        #pragma unroll
        for (int ct = 0; ct < 8; ++ct) {
            const int c = st * 8 + ct;         // global 16-col tile 0..63
            const int colb = (ct * 16 + m) * 8;
            short8 b0 = *(const short8*)&sB[(colb + (quad ^ (m & 7))) * 8];
            short8 b1 = *(const short8*)&sB[(colb + ((4 + quad) ^ (m & 7))) * 8];
            f32x4 acc0 = {0.f, 0.f, 0.f, 0.f};
            f32x4 acc1 = {0.f, 0.f, 0.f, 0.f};
            acc0 = __builtin_amdgcn_mfma_f32_16x16x32_bf16(a[0][0], b0, acc0, 0, 0, 0);
            acc0 = __builtin_amdgcn_mfma_f32_16x16x32_bf16(a[0][1], b1, acc0, 0, 0, 0);
            acc1 = __builtin_amdgcn_mfma_f32_16x16x32_bf16(a[1][0], b0, acc1, 0, 0, 0);
            acc1 = __builtin_amdgcn_mfma_f32_16x16x32_bf16(a[1][1], b1, acc1, 0, 0, 0);
            const float en = sEn[c * 16 + m];
            #pragma unroll
            for (int r = 0; r < 4; ++r) {
                float v0 = fmaf(-2.f, acc0[r], en);
                bool p1 = v0 < v1[0][r];
                bool p2 = v0 < v2[0][r];
                v2[0][r] = p1 ? v1[0][r] : (p2 ? v0 : v2[0][r]);
                k2[0][r] = p1 ? k1[0][r] : (p2 ? c : k2[0][r]);
                v1[0][r] = p1 ? v0 : v1[0][r];
                k1[0][r] = p1 ? c : k1[0][r];
                float w1 = fmaf(-2.f, acc1[r], en);
                bool q1 = w1 < v1[1][r];
                bool q2 = w1 < v2[1][r];
                v2[1][r] = q1 ? v1[1][r] : (q2 ? w1 : v2[1][r]);
                k2[1][r] = q1 ? k1[1][r] : (q2 ? c : k2[1][r]);
                v1[1][r] = q1 ? w1 : v1[1][r];
                k1[1][r] = q1 ? c : k1[1][r];
            }
        }
        __syncthreads();
    }

    // exact re-evaluation (fp32 z from global, E column from Et/E);
    // lexicographic (d, k) min = np first-occurrence tie-break
    float la = 0.f;
    #pragma unroll
    for (int rt = 0; rt < 2; ++rt) {
        #pragma unroll
        for (int r = 0; r < 4; ++r) {
            float vb = v1[rt][r];
            #pragma unroll
            for (int mask = 1; mask <= 8; mask <<= 1)
                vb = fminf(vb, __shfl_xor(vb, mask));
            const int rowl = w * 32 + rt * 16 + quad * 4 + r;
            const float zn = sZn[rowl];
            const float* zr = z + (b * 128 + rowl) * 64;
            float d = 3.4e38f;
            int kk = 0x7fffffff;
            if (v1[rt][r] <= vb + MARGIN) {
                kk = k1[rt][r] * 16 + m;
                d = USE_ET ? np_dist<1>(zr, Et + kk * 64, zn, sEn[kk])
                           : np_dist<1024>(zr, E + kk, zn, sEn[kk]);
            }
            if (v2[rt][r] <= vb + MARGIN) {
                int kc = k2[rt][r] * 16 + m;
                float dd = USE_ET ? np_dist<1>(zr, Et + kc * 64, zn, sEn[kc])
                                  : np_dist<1024>(zr, E + kc, zn, sEn[kc]);
                if (dd < d || (dd == d && kc < kk)) { d = dd; kk = kc; }
            }
            #pragma unroll
            for (int mask = 1; mask <= 8; mask <<= 1) {
                float d2 = __shfl_xor(d, mask);
                int c2 = __shfl_xor(kk, mask);
                bool take = (d2 < d) || (d2 == d && c2 < kk);
                d = take ? d2 : d;
                kk = take ? c2 : kk;
            }
            if (m == 0) {
                sIdx[rowl] = kk;
                la += d;
            }
        }
    }
    __syncthreads();

    // gather: 2 lanes/row, 32 dims each (contiguous from Et when available)
    {
        const int row_local = w * 32 + (l >> 1);
        const int half = l & 1;
        const int idx = sIdx[row_local];
        union { float s[32]; float4 f[8]; } tmp;
        if (USE_ET) {
            const float4* src = (const float4*)(Et + idx * 64 + half * 32);
            #pragma unroll
            for (int q4 = 0; q4 < 8; ++q4) tmp.f[q4] = src[q4];
        } else {
            #pragma unroll
            for (int dd = 0; dd < 32; ++dd) tmp.s[dd] = E[(half * 32 + dd) * 1024 + idx];
        }
        float4* dst = (float4*)(out + (b * 128 + row_local) * 64 + half * 32);
        #pragma unroll
        for (int q4 = 0; q4 < 8; ++q4) dst[q4] = tmp.f[q4];
    }

    #pragma unroll
    for (int mask = 32; mask >= 1; mask >>= 1) la += __shfl_xor(la, mask);
    if (l == 0) sRed[w] = la;
    __syncthreads();
    if (tid == 0) atomicAdd(ws_loss, sRed[0] + sRed[1] + sRed[2] + sRed[3]);
}

// ---------------------------------------------------------------------------
// Kernel 3: loss scalar (fp32) at out[8388608]
// ---------------------------------------------------------------------------
__global__ void vq_final(const float* __restrict__ ws_loss,
                         float* __restrict__ out) {
    out[8388608] = (*ws_loss) * (1.25f / 8388608.f);
}

extern "C" void kernel_launch(void* const* d_in, const int* in_sizes, int n_in,
                              void* d_out, int out_size, void* d_ws, size_t ws_size,
                              hipStream_t stream) {
    const float* z = (const float*)d_in[0];  // fp32 [131072,64]
    const float* E = (const float*)d_in[1];  // fp32 [64,1024]
    float* out = (float*)d_out;              // fp32 [8388609]

    char* ws = (char*)d_ws;
    float* loss = (float*)ws;            // 4 B
    float* enorm = (float*)(ws + 128);   // 4 KB
    float* Et = (float*)(ws + 8192);     // 256 KB (optional)
    const bool useEt = ws_size >= (size_t)(8192 + 65536 * 4);

    if (useEt) {
        vq_prep_t<<<256, 256, 0, stream>>>(E, Et);
        vq_prep<1><<<4, 256, 0, stream>>>(Et, loss, enorm);
        vq_main<true><<<1024, 256, 0, stream>>>(z, E, Et, enorm, loss, out);
    } else {
        vq_prep<1024><<<4, 256, 0, stream>>>(E, loss, enorm);
        vq_main<false><<<1024, 256, 0, stream>>>(z, E, Et, enorm, loss, out);
    }
    vq_final<<<1, 1, 0, stream>>>(loss, out);
}